// Round 10
// baseline (120.039 us; speedup 1.0000x reference)
//
#include <hip/hip_runtime.h>

// RNNAdder round 9: r8 skeleton (256x256, 4 waves, packed-pair ring, spread
// projection) with chain shaves:
//  (1) recurrence = 4 INDEPENDENT MFMA partials + tree add (chain depth 1).
//  (2) 2*log2(e) folded into Wint/Pf -> exp2 directly (no on-chain mul).
//  (3) hi/lo split via mantissa-mask RTZ (no f16->f32 cvts on chain).
//  (4) xp MFMA after ds_writes (overlaps write drain); LUT read issued at
//      step top from a mask prefetched 2 steps ahead.
//  (5) 4 bank-offset LUT copies (per-quad) to cut data-dependent conflicts.

typedef _Float16 half8 __attribute__((ext_vector_type(8)));
typedef __fp16 fp16x2 __attribute__((ext_vector_type(2)));
typedef float floatx4 __attribute__((ext_vector_type(4)));

#define MFMA16(A, B, C) __builtin_amdgcn_mfma_f32_16x16x32_f16((A), (B), (C), 0, 0, 0)
#define BARRIER() asm volatile("s_waitcnt lgkmcnt(0)\n\ts_barrier" ::: "memory")
#define TWO_LOG2E 2.885390081777927f

// pool dword layout
#define LUT_DW  17408                 // ring: 16 slots x 16 rows x 68 dw
#define NP_DW   21536                 // LUT: 4 copies x 1032 dw (8-dw skew)
#define POOL_DW 23616                 // np: 130 rows x 16 ; total 94.5 KB

__global__ __launch_bounds__(256)
void rnn_mfma(const int* __restrict__ num1, const int* __restrict__ num2,
              const float* __restrict__ E, const float* __restrict__ Wxh,
              const float* __restrict__ Whh, const float* __restrict__ bias,
              const float* __restrict__ Wd, const float* __restrict__ bd,
              float* __restrict__ out)
{
    __shared__ __align__(16) int pool[POOL_DW];
    int* lutI  = pool + LUT_DW;
    int* numpk = pool + NP_DW;

    const int tid  = threadIdx.x;
    const int w    = tid >> 6;
    const int lane = tid & 63;
    const int c    = lane & 15;
    const int q    = lane >> 4;
    const int qs   = q * 8;
    const int g    = blockIdx.x;

    // ---- startup staging (overlaid on ring slots 0..5) ----
    float* WhhS = (float*)pool;           // 4096
    float* P1t  = (float*)(pool + 4096);  // 640
    float* P2t  = (float*)(pool + 4736);  // 640
    float* WdS  = (float*)(pool + 5376);  // 640
    for (int i = tid; i < 4096; i += 256) WhhS[i] = Whh[i];
    for (int i = tid; i < 640;  i += 256) WdS[i]  = Wd[i];
    for (int idx = tid; idx < 640; idx += 256) {
        int v = idx >> 6, jj = idx & 63;
        float s1 = bias[jj], s2 = 0.f;
        #pragma unroll
        for (int i = 0; i < 32; ++i) {
            float e = E[v * 32 + i];
            s1 = fmaf(e, Wxh[i * 64 + jj], s1);
            s2 = fmaf(e, Wxh[(32 + i) * 64 + jj], s2);
        }
        P1t[idx] = s1;  // bias folded in
        P2t[idx] = s2;
    }
    {   // one-hot LUT: 4 bank-skewed copies, 256 entries x 4 dw each
        int e = tid;
        #pragma unroll
        for (int j = 0; j < 4; ++j) {
            int v = (((e >> (2 * j)) & 1) ? 0x3C00 : 0)
                  | (((e >> (2 * j + 1)) & 1) ? 0x3C000000 : 0);
            #pragma unroll
            for (int cp = 0; cp < 4; ++cp)
                lutI[cp * 1032 + e * 4 + j] = v;
        }
    }
    // token bit-masks (rows 128..129 zero-padded)
    for (int idx = tid; idx < 2080; idx += 256) {
        int m = idx & 15, t = idx >> 4;
        int s = g * 16 + m;
        numpk[t * 16 + m] = (t < 128)
            ? ((1 << num1[s * 128 + t]) | (1 << (num2[s * 128 + t] + 10))) : 0;
    }
    __syncthreads();

    // ---- resident B-fragments ----
    // Wint[kt][2p] = 2log2e * W[kt*16+q*4+p][n]; [2p+1] = same/64. Wd unscaled.
    half8 Wint[4], Wdint[4], Pf;
    #pragma unroll
    for (int kt = 0; kt < 4; ++kt)
        #pragma unroll
        for (int p = 0; p < 4; ++p) {
            int k = kt * 16 + q * 4 + p;
            float wv = WhhS[k * 64 + w * 16 + c] * TWO_LOG2E;
            Wint[kt][2 * p]     = (_Float16)wv;
            Wint[kt][2 * p + 1] = (_Float16)(wv * 0.015625f);
            float dv = (c < 10) ? WdS[k * 10 + c] : 0.f;
            Wdint[kt][2 * p]     = (_Float16)dv;
            Wdint[kt][2 * p + 1] = (_Float16)(dv * 0.015625f);
        }
    #pragma unroll
    for (int j = 0; j < 8; ++j) {   // Pf: k = q*8+j mapping, scaled
        int i2 = qs + j;
        float pv = (i2 < 10) ? P1t[i2 * 64 + w * 16 + c]
                 : (i2 < 20) ? P2t[(i2 - 10) * 64 + w * 16 + c] : 0.f;
        Pf[j] = (_Float16)(pv * TWO_LOG2E);
    }
    float bdv = (c < 10) ? bd[c] : 0.f;
    __syncthreads();   // staging region free for ring reuse

    // ---- zero slot 15 (h_{-1}=0) ----
    for (int i = tid; i < 1088; i += 256) pool[15 * 1088 + i] = 0;
    __syncthreads();

    // ---- loop-invariant addresses (dword units) ----
    const int rBase = c * 68 + q * 4;
    const int wBase = (q * 4) * 68 + w * 16 + c;
    const int lutQ  = q * 1032;

    float* outP[2][4];
    #pragma unroll
    for (int u = 0; u < 2; ++u)
        #pragma unroll
        for (int r = 0; r < 4; ++r)
            outP[u][r] = out + (((g * 16 + q * 4 + r) * 128) + 2 * w + u) * 10 + c;

    const floatx4 zero4 = {0.f, 0.f, 0.f, 0.f};

    // ---- prologue: Cxp for t=0; mask for t=1 ----
    floatx4 Cxp;
    {
        int mk0 = numpk[c];
        half8 Aoh = *(const half8*)&lutI[lutQ + ((mk0 >> qs) & 0xFF) * 4];
        Cxp = MFMA16(Aoh, Pf, zero4);
    }
    int mkN = numpk[16 + c];   // mask for step 1

    for (int half = 0; half < 16; ++half) {
        const int sb  = (half & 1) * 8;
        const int npo = half * 128 + c;
        #pragma unroll
        for (int i = 0; i < 8; ++i) {
            // LUT read for step t+1 (mask prefetched 2 steps ago) + np for t+2
            half8 Aoh = *(const half8*)&lutI[lutQ + ((mkN >> qs) & 0xFF) * 4];
            int mkN2 = numpk[npo + (i + 2) * 16];

            const int spw = sb + i;
            const int spr = (i == 0) ? ((sb ^ 8) + 7) : (sb + i - 1);

            // packed A-frags: 4 x b128
            half8 A0 = *(const half8*)&pool[spr * 1088 + rBase];
            half8 A1 = *(const half8*)&pool[spr * 1088 + rBase + 16];
            half8 A2 = *(const half8*)&pool[spr * 1088 + rBase + 32];
            half8 A3 = *(const half8*)&pool[spr * 1088 + rBase + 48];

            // recurrence: 4 INDEPENDENT partials (chain depth 1)
            floatx4 Ca = MFMA16(A0, Wint[0], Cxp);
            floatx4 Cb = MFMA16(A1, Wint[1], zero4);
            floatx4 Cc = MFMA16(A2, Wint[2], zero4);
            floatx4 Cd = MFMA16(A3, Wint[3], zero4);

            // tanh (input pre-scaled by 2log2e) + RTZ hi/lo split + 4 b32 writes
            float hv[4];
            #pragma unroll
            for (int r = 0; r < 4; ++r) {
                float x  = (Ca[r] + Cb[r]) + (Cc[r] + Cd[r]);
                float e2 = __builtin_amdgcn_exp2f(x);
                hv[r] = 1.f - 2.f * __builtin_amdgcn_rcpf(e2 + 1.f);
            }
            #pragma unroll
            for (int p = 0; p < 2; ++p) {
                unsigned b0 = __builtin_bit_cast(unsigned, hv[2 * p])     & 0xFFFFE000u;
                unsigned b1 = __builtin_bit_cast(unsigned, hv[2 * p + 1]) & 0xFFFFE000u;
                float a0 = __builtin_bit_cast(float, b0);
                float a1 = __builtin_bit_cast(float, b1);
                fp16x2 ph = __builtin_amdgcn_cvt_pkrtz(a0, a1);          // exact
                fp16x2 pl = __builtin_amdgcn_cvt_pkrtz((hv[2 * p] - a0) * 64.f,
                                                       (hv[2 * p + 1] - a1) * 64.f);
                unsigned phu = __builtin_bit_cast(unsigned, ph);
                unsigned plu = __builtin_bit_cast(unsigned, pl);
                unsigned w0 = __builtin_amdgcn_perm(plu, phu, 0x05040100u);
                unsigned w1 = __builtin_amdgcn_perm(plu, phu, 0x07060302u);
                pool[spw * 1088 + wBase + (2 * p) * 68]     = (int)w0;
                pool[spw * 1088 + wBase + (2 * p + 1) * 68] = (int)w1;
            }

            // xp MFMA for t+1 AFTER the writes: overlaps the write drain
            Cxp = MFMA16(Aoh, Pf, zero4);
            mkN = mkN2;

            // spread projection: u=0 at i==2, u=1 at i==6 (prev half's slots)
            if ((i == 2 || i == 6) && half > 0) {
                const int u   = (i == 6);
                const int sbp = (half & 1) ? 0 : 8;
                const int sl  = (sbp + 2 * w + u) * 1088 + rBase;
                half8 P0 = *(const half8*)&pool[sl];
                half8 P1 = *(const half8*)&pool[sl + 16];
                half8 P2 = *(const half8*)&pool[sl + 32];
                half8 P3 = *(const half8*)&pool[sl + 48];
                floatx4 Cp = MFMA16(P0, Wdint[0], zero4);
                Cp         = MFMA16(P1, Wdint[1], Cp);
                Cp         = MFMA16(P2, Wdint[2], Cp);
                Cp         = MFMA16(P3, Wdint[3], Cp);
                if (c < 10) {
                    #pragma unroll
                    for (int r = 0; r < 4; ++r)
                        outP[u][r][-80] = Cp[r] + bdv;
                }
            }

            BARRIER();   // lgkmcnt-only: global stores stay in flight
        }
        #pragma unroll
        for (int u = 0; u < 2; ++u)
            #pragma unroll
            for (int r = 0; r < 4; ++r)
                outP[u][r] += 80;   // +8 steps
    }

    // ---- epilogue: steps 120..127 (slots 8..15) ----
    #pragma unroll
    for (int u = 0; u < 2; ++u) {
        const int sl = (8 + 2 * w + u) * 1088 + rBase;
        half8 P0 = *(const half8*)&pool[sl];
        half8 P1 = *(const half8*)&pool[sl + 16];
        half8 P2 = *(const half8*)&pool[sl + 32];
        half8 P3 = *(const half8*)&pool[sl + 48];
        floatx4 Cp = MFMA16(P0, Wdint[0], zero4);
        Cp         = MFMA16(P1, Wdint[1], Cp);
        Cp         = MFMA16(P2, Wdint[2], Cp);
        Cp         = MFMA16(P3, Wdint[3], Cp);
        if (c < 10) {
            #pragma unroll
            for (int r = 0; r < 4; ++r)
                outP[u][r][-80] = Cp[r] + bdv;
        }
    }
}

extern "C" void kernel_launch(void* const* d_in, const int* in_sizes, int n_in,
                              void* d_out, int out_size, void* d_ws, size_t ws_size,
                              hipStream_t stream) {
    const int*   num1 = (const int*)d_in[0];
    const int*   num2 = (const int*)d_in[1];
    const float* E    = (const float*)d_in[2];
    const float* Wxh  = (const float*)d_in[3];
    const float* Whh  = (const float*)d_in[4];
    const float* b    = (const float*)d_in[5];
    const float* Wd   = (const float*)d_in[6];
    const float* bd   = (const float*)d_in[7];
    float* out = (float*)d_out;
    rnn_mfma<<<256, 256, 0, stream>>>(num1, num2, E, Wxh, Whh, b, Wd, bd, out);
}